// Round 1
// baseline (50289.203 us; speedup 1.0000x reference)
//
#include <hip/hip_runtime.h>
#include <stdint.h>

#define NB    64
#define LSEQ  2048
#define IND   128
#define HID   256
#define ACTD  18
#define G3    768            // 3*HID
#define MROWS (NB*LSEQ)      // 131072
#define JGROUPS 8

// ---------------- dtype helpers (manual bf16 to avoid header ABI issues) ------------
__device__ __forceinline__ float bf2f(unsigned short u) { return __uint_as_float(((unsigned)u) << 16); }
__device__ __forceinline__ unsigned short f2bf(float f) {
  unsigned u = __float_as_uint(f);
  return (unsigned short)((u + 0x7FFFu + ((u >> 16) & 1u)) >> 16);
}
template<typename T> __device__ __forceinline__ float ldv(const T* p);
template<> __device__ __forceinline__ float ldv<float>(const float* p) { return *p; }
template<> __device__ __forceinline__ float ldv<unsigned short>(const unsigned short* p) { return bf2f(*p); }
template<typename T> __device__ __forceinline__ void stv(T* p, float v);
template<> __device__ __forceinline__ void stv<float>(float* p, float v) { *p = v; }
template<> __device__ __forceinline__ void stv<unsigned short>(unsigned short* p, float v) { *p = f2bf(v); }
template<typename T> __device__ __forceinline__ float4 ld4(const T* p);
template<> __device__ __forceinline__ float4 ld4<float>(const float* p) { return *(const float4*)p; }
template<> __device__ __forceinline__ float4 ld4<unsigned short>(const unsigned short* p) {
  ushort4 u = *(const ushort4*)p;
  float4 r; r.x = bf2f(u.x); r.y = bf2f(u.y); r.z = bf2f(u.z); r.w = bf2f(u.w); return r;
}

// ---------------- prep: c[n] = last done index, h_buf init, counter zeroing ---------
__global__ void rnnq_prep(const int* __restrict__ dones, const float* __restrict__ h0,
                          float* __restrict__ h_buf, int* __restrict__ c_arr,
                          int* __restrict__ counters) {
  const int n = blockIdx.x;     // 0..63
  const int t = threadIdx.x;    // 0..255
  int m = 0;
  for (int i = t; i < LSEQ; i += 256) if (dones[n*LSEQ + i]) m = i;  // i increasing -> keeps max
  __shared__ int red[256];
  red[t] = m;
  __syncthreads();
  for (int s = 128; s > 0; s >>= 1) {
    if (t < s) red[t] = red[t] > red[t+s] ? red[t] : red[t+s];
    __syncthreads();
  }
  if (t == 0) c_arr[n] = red[0];
  const float hv = h0[n*HID + t];
  h_buf[(size_t)n*HID + t] = hv;          // main row n
  h_buf[(size_t)(64+n)*HID + t] = hv;     // virtual row 64+n (reset-at-t0 handles zeroing)
  if (n == 0) {
    counters[t] = 0; counters[256+t] = 0; counters[512+t] = 0; counters[768+t] = 0;
  }
}

// ---------------- generic fp32-accumulate GEMM: C[M,N] = op(A[M,K]) * W[N,K]^T + b --
// tile 64 x 128, K-chunks of 32, micro 4x8 per thread, 256 threads
template<typename IT, typename OT, bool RELU_IN, bool RELU_OUT, int K>
__global__ __launch_bounds__(256) void rnnq_gemm(const IT* __restrict__ A, const float* __restrict__ W,
                                                 const float* __restrict__ bias, OT* __restrict__ C,
                                                 int N) {
  __shared__ float At[32][68];    // transposed [k][row], 68 pad: 16B-aligned rows
  __shared__ float Wt[32][136];   // transposed [k][col]
  const int t  = threadIdx.x;
  const long m0 = (long)blockIdx.x * 64;
  const int n0 = blockIdx.y * 128;
  const int ty = t >> 4, tx = t & 15;
  const int sr = t >> 2, skq = (t & 3) * 4;     // A staging: row, k-quad
  const int wc = t >> 1, wkh = (t & 1) * 16;    // W staging: col, k-half
  float acc[4][8] = {{0.f}};
  for (int kc = 0; kc < K; kc += 32) {
    float4 a0 = ld4(A + (m0 + sr) * (size_t)K + kc + skq);
    float4 a1 = ld4(A + (m0 + sr) * (size_t)K + kc + skq + 16);
    if (RELU_IN) {
      a0.x = fmaxf(a0.x, 0.f); a0.y = fmaxf(a0.y, 0.f); a0.z = fmaxf(a0.z, 0.f); a0.w = fmaxf(a0.w, 0.f);
      a1.x = fmaxf(a1.x, 0.f); a1.y = fmaxf(a1.y, 0.f); a1.z = fmaxf(a1.z, 0.f); a1.w = fmaxf(a1.w, 0.f);
    }
    const float* wp = W + (size_t)(n0 + wc) * K + kc + wkh;
    float4 w0 = *(const float4*)(wp + 0);
    float4 w1 = *(const float4*)(wp + 4);
    float4 w2 = *(const float4*)(wp + 8);
    float4 w3 = *(const float4*)(wp + 12);
    At[skq+0][sr] = a0.x; At[skq+1][sr] = a0.y; At[skq+2][sr] = a0.z; At[skq+3][sr] = a0.w;
    At[skq+16][sr] = a1.x; At[skq+17][sr] = a1.y; At[skq+18][sr] = a1.z; At[skq+19][sr] = a1.w;
    Wt[wkh+0][wc] = w0.x; Wt[wkh+1][wc] = w0.y; Wt[wkh+2][wc] = w0.z; Wt[wkh+3][wc] = w0.w;
    Wt[wkh+4][wc] = w1.x; Wt[wkh+5][wc] = w1.y; Wt[wkh+6][wc] = w1.z; Wt[wkh+7][wc] = w1.w;
    Wt[wkh+8][wc] = w2.x; Wt[wkh+9][wc] = w2.y; Wt[wkh+10][wc] = w2.z; Wt[wkh+11][wc] = w2.w;
    Wt[wkh+12][wc] = w3.x; Wt[wkh+13][wc] = w3.y; Wt[wkh+14][wc] = w3.z; Wt[wkh+15][wc] = w3.w;
    __syncthreads();
    #pragma unroll
    for (int k = 0; k < 32; ++k) {
      const float4 av  = *(const float4*)&At[k][ty*4];
      const float4 bv0 = *(const float4*)&Wt[k][tx*8];
      const float4 bv1 = *(const float4*)&Wt[k][tx*8+4];
      const float am[4] = {av.x, av.y, av.z, av.w};
      const float bm[8] = {bv0.x, bv0.y, bv0.z, bv0.w, bv1.x, bv1.y, bv1.z, bv1.w};
      #pragma unroll
      for (int i = 0; i < 4; ++i)
        #pragma unroll
        for (int jj = 0; jj < 8; ++jj)
          acc[i][jj] = fmaf(am[i], bm[jj], acc[i][jj]);
    }
    __syncthreads();
  }
  #pragma unroll
  for (int i = 0; i < 4; ++i) {
    const long r = m0 + ty*4 + i;
    OT* cp = C + r * (size_t)N + n0 + tx*8;
    #pragma unroll
    for (int jj = 0; jj < 8; ++jj) {
      float v = acc[i][jj] + bias[n0 + tx*8 + jj];
      if (RELU_OUT) v = fmaxf(v, 0.f);
      stv(cp + jj, v);
    }
  }
}

// ---------------- fc2: Q[131072,18] = X[131072,256] * W2[18,256]^T + b2 -------------
template<typename YT>
__global__ __launch_bounds__(256) void rnnq_fc2(const YT* __restrict__ X, const float* __restrict__ W2,
                                                const float* __restrict__ b2, float* __restrict__ Q) {
  __shared__ float xs[32][260];
  __shared__ float ws2[ACTD][260];
  const int t = threadIdx.x;
  const long r0 = (long)blockIdx.x * 32;
  for (int i = t; i < 32*64; i += 256) {
    const int r = i >> 6, c4 = (i & 63) * 4;
    const float4 v = ld4(X + (r0 + r) * (size_t)HID + c4);
    *(float4*)&xs[r][c4] = v;
  }
  for (int i = t; i < ACTD*64; i += 256) {
    const int a = i >> 6, c4 = (i & 63) * 4;
    *(float4*)&ws2[a][c4] = *(const float4*)(W2 + a*HID + c4);
  }
  __syncthreads();
  for (int idx = t; idx < 32*ACTD; idx += 256) {
    const int r = idx / ACTD, a = idx - r*ACTD;
    float s0 = 0.f, s1 = 0.f;
    #pragma unroll
    for (int k4 = 0; k4 < HID/4; k4 += 2) {
      const float4 xv = *(const float4*)&xs[r][k4*4];
      const float4 wv = *(const float4*)&ws2[a][k4*4];
      s0 = fmaf(xv.x, wv.x, s0); s0 = fmaf(xv.y, wv.y, s0);
      s0 = fmaf(xv.z, wv.z, s0); s0 = fmaf(xv.w, wv.w, s0);
      const float4 xv2 = *(const float4*)&xs[r][k4*4+4];
      const float4 wv2 = *(const float4*)&ws2[a][k4*4+4];
      s1 = fmaf(xv2.x, wv2.x, s1); s1 = fmaf(xv2.y, wv2.y, s1);
      s1 = fmaf(xv2.z, wv2.z, s1); s1 = fmaf(xv2.w, wv2.w, s1);
    }
    Q[(r0 + r) * ACTD + a] = s0 + s1 + b2[a];
  }
}

// ---------------- the fused scan: 128 rows (64 main + 64 virtual), 2048 steps -------
// Block = (row-group of RG rows) x (j-slice of 32 hidden units). 256 threads:
// thread = (jl = t>>3 in 0..31, ks = t&7 k-slice). Weights in registers (96 fp32).
// Per-row-group barrier among JGROUPS=8 blocks via device-scope counter.
template<typename GIT, int RG>
__global__ __launch_bounds__(256, 2) void rnnq_scan(
    const GIT* __restrict__ gi, const int* __restrict__ dones,
    const float* __restrict__ w_hh, const float* __restrict__ b_hh, const float* __restrict__ b_ih,
    const int* __restrict__ c_arr, float* __restrict__ h_buf, int* __restrict__ counters,
    float* __restrict__ gru_out, float* __restrict__ next_hx) {
  constexpr int NRG = 128 / RG;           // row groups
  constexpr int NGRAN = (RG * HID / 2) / 256;  // float2 staging granules per thread (1 or 2)
  const int b  = blockIdx.x;
  const int jg = b / NRG;                 // 0..7
  const int rg = b % NRG;                 // same-XCD heuristic: rg%8 stable across jg
  const int r0 = rg * RG;
  const int j0 = jg * 32;
  const int t  = threadIdx.x;
  const int jl = t >> 3;                  // 0..31
  const int ks = t & 7;                   // 0..7
  const int ks4 = ks * 4;
  const int j = j0 + jl;

  // --- persistent weight registers: thread's k-set = { i4*32 + ks*4 + c } ---
  float wr[32], wz[32], wn[32];
  #pragma unroll
  for (int i4 = 0; i4 < 8; ++i4) {
    const float4 va = *(const float4*)&w_hh[(size_t)j*HID + i4*32 + ks4];
    wr[i4*4+0] = va.x; wr[i4*4+1] = va.y; wr[i4*4+2] = va.z; wr[i4*4+3] = va.w;
    const float4 vb = *(const float4*)&w_hh[(size_t)(HID + j)*HID + i4*32 + ks4];
    wz[i4*4+0] = vb.x; wz[i4*4+1] = vb.y; wz[i4*4+2] = vb.z; wz[i4*4+3] = vb.w;
    const float4 vc = *(const float4*)&w_hh[(size_t)(2*HID + j)*HID + i4*32 + ks4];
    wn[i4*4+0] = vc.x; wn[i4*4+1] = vc.y; wn[i4*4+2] = vc.z; wn[i4*4+3] = vc.w;
  }
  const float bhr = b_hh[j], bhz = b_hh[HID+j], bhn = b_hh[2*HID+j];
  const float bir = b_ih[j], biz = b_ih[HID+j], bin_ = b_ih[2*HID+j];

  // --- epilogue role: lane ks < RG handles (row = r0+ks, hidden j) ---
  const bool epi = (ks < RG);
  const int my_row = r0 + ks;
  const int my_n = my_row & 63;
  const int my_off = (my_row < 64) ? 0 : c_arr[my_n];
  const bool is_main = (my_row < 64);

  // --- staging role: NGRAN float2 granules per thread ---
  int s_row[NGRAN], s_col[NGRAN], s_off[NGRAN], s_n[NGRAN];
  #pragma unroll
  for (int g = 0; g < NGRAN; ++g) {
    const int i = t + g*256;
    s_row[g] = i / (HID/2);
    s_col[g] = (i % (HID/2)) * 2;
    const int grow = r0 + s_row[g];
    s_n[g] = grow & 63;
    s_off[g] = (grow < 64) ? 0 : c_arr[grow & 63];
  }

  __shared__ float h_s[RG][264];
  int* cnt = counters + rg * 16;

  // initial stage (step 0 reads h_buf[0], reset if dones[idx0])
  #pragma unroll
  for (int g = 0; g < NGRAN; ++g) {
    const int idx0 = s_off[g];
    const int dd = dones[s_n[g]*LSEQ + idx0];
    float2 h2 = *(const float2*)&h_buf[(size_t)(r0 + s_row[g])*HID + s_col[g]];
    if (dd) { h2.x = 0.f; h2.y = 0.f; }
    h_s[s_row[g]][s_col[g]] = h2.x;
    h_s[s_row[g]][s_col[g]+1] = h2.y;
  }
  // gi for step 0
  float gr = 0.f, gz = 0.f, gn = 0.f;
  if (epi) {
    const GIT* gp = gi + (size_t)(my_n*LSEQ + my_off) * G3;
    gr = ldv(gp + j); gz = ldv(gp + HID + j); gn = ldv(gp + 2*HID + j);
  }
  __syncthreads();

  int dn[NGRAN];
  #pragma unroll
  for (int g = 0; g < NGRAN; ++g) dn[g] = 0;

  for (int step = 0; step < LSEQ; ++step) {
    // partial matvec over this thread's 32 k's, for RG rows x 3 gates
    float s_r[RG], s_z[RG], s_nn[RG];
    #pragma unroll
    for (int r = 0; r < RG; ++r) {
      float a0=0.f, a1=0.f, b0=0.f, b1=0.f, c0=0.f, c1=0.f;
      #pragma unroll
      for (int i4 = 0; i4 < 8; ++i4) {
        const float4 h4 = *(const float4*)&h_s[r][i4*32 + ks4];
        a0 = fmaf(wr[i4*4+0], h4.x, a0); a1 = fmaf(wr[i4*4+1], h4.y, a1);
        a0 = fmaf(wr[i4*4+2], h4.z, a0); a1 = fmaf(wr[i4*4+3], h4.w, a1);
        b0 = fmaf(wz[i4*4+0], h4.x, b0); b1 = fmaf(wz[i4*4+1], h4.y, b1);
        b0 = fmaf(wz[i4*4+2], h4.z, b0); b1 = fmaf(wz[i4*4+3], h4.w, b1);
        c0 = fmaf(wn[i4*4+0], h4.x, c0); c1 = fmaf(wn[i4*4+1], h4.y, c1);
        c0 = fmaf(wn[i4*4+2], h4.z, c0); c1 = fmaf(wn[i4*4+3], h4.w, c1);
      }
      s_r[r] = a0 + a1; s_z[r] = b0 + b1; s_nn[r] = c0 + c1;
    }
    // prefetch next-step dones for staging (hide latency across compute+barrier)
    if (step + 1 < LSEQ) {
      #pragma unroll
      for (int g = 0; g < NGRAN; ++g) {
        const int nidx = s_off[g] + step + 1;
        dn[g] = (nidx < LSEQ) ? dones[s_n[g]*LSEQ + nidx] : 0;
      }
    }
    // butterfly all-reduce over the 8 k-slices (lane bits 0..2)
    #pragma unroll
    for (int r = 0; r < RG; ++r) {
      s_r[r] += __shfl_xor(s_r[r], 1, 64); s_r[r] += __shfl_xor(s_r[r], 2, 64); s_r[r] += __shfl_xor(s_r[r], 4, 64);
      s_z[r] += __shfl_xor(s_z[r], 1, 64); s_z[r] += __shfl_xor(s_z[r], 2, 64); s_z[r] += __shfl_xor(s_z[r], 4, 64);
      s_nn[r] += __shfl_xor(s_nn[r], 1, 64); s_nn[r] += __shfl_xor(s_nn[r], 2, 64); s_nn[r] += __shfl_xor(s_nn[r], 4, 64);
    }
    if (epi) {
      const int row = ks;
      const float h_old = h_s[row][j];    // post-reset h, used for blend
      const float rr = 1.f / (1.f + __expf(-(gr + s_r[row] + bhr)));
      const float zz = 1.f / (1.f + __expf(-(gz + s_z[row] + bhz)));
      const float nn = tanhf(gn + rr * (s_nn[row] + bhn));
      const float hnew = (1.f - zz) * nn + zz * h_old;
      h_buf[(size_t)((step + 1) & 1) * 128 * HID + (size_t)my_row * HID + j] = hnew;
      if (is_main) {
        gru_out[((size_t)my_n * LSEQ + step) * HID + j] = hnew;
      } else if (step == LSEQ - 1) {
        next_hx[my_n * HID + j] = hnew;
      }
      if (step + 1 < LSEQ) {
        const int nidx = my_off + step + 1;
        if (nidx < LSEQ) {
          const GIT* gp = gi + (size_t)(my_n*LSEQ + nidx) * G3;
          gr = ldv(gp + j); gz = ldv(gp + HID + j); gn = ldv(gp + 2*HID + j);
        } else { gr = bir; gz = biz; gn = bin_; }
      }
    }
    if (step == LSEQ - 1) break;
    __syncthreads();                       // all h-writes issued; h_s reads done
    if (t == 0) {
      __builtin_amdgcn_fence(__ATOMIC_RELEASE, "agent");
      __hip_atomic_fetch_add(cnt, 1, __ATOMIC_RELAXED, __HIP_MEMORY_SCOPE_AGENT);
      const int target = JGROUPS * (step + 1);
      while (__hip_atomic_load(cnt, __ATOMIC_RELAXED, __HIP_MEMORY_SCOPE_AGENT) < target)
        __builtin_amdgcn_s_sleep(1);
    }
    __syncthreads();
    __builtin_amdgcn_fence(__ATOMIC_ACQUIRE, "agent");
    // re-stage h for next step from the other buffer
    #pragma unroll
    for (int g = 0; g < NGRAN; ++g) {
      float2 h2 = *(const float2*)&h_buf[(size_t)((step + 1) & 1) * 128 * HID +
                                         (size_t)(r0 + s_row[g]) * HID + s_col[g]];
      if (dn[g]) { h2.x = 0.f; h2.y = 0.f; }
      h_s[s_row[g]][s_col[g]] = h2.x;
      h_s[s_row[g]][s_col[g]+1] = h2.y;
    }
    __syncthreads();
  }
}

// ---------------- host-side pipeline ----------------
template<typename GIT, typename YT>
static void run_pipeline(const float* state, const float* h0, const int* dones,
                         const float* w_ih, const float* w_hh, const float* b_ih, const float* b_hh,
                         const float* fc0_w, const float* fc0_b, const float* fc1_w, const float* fc1_b,
                         const float* fc2_w, const float* fc2_b,
                         float* q_out, float* gru_out, float* hx_out,
                         char* ws, size_t y1_off, size_t tail_off, hipStream_t stream) {
  GIT* gi = (GIT*)ws;
  YT* y0 = (YT*)ws;                       // aliases gi (gi dead after scan)
  YT* y1 = (YT*)(ws + y1_off);
  float* h_buf   = (float*)(ws + tail_off);
  int* c_arr     = (int*)(ws + tail_off + 262144);
  int* counters  = (int*)(ws + tail_off + 262144 + 256);

  rnnq_prep<<<64, 256, 0, stream>>>(dones, h0, h_buf, c_arr, counters);
  rnnq_gemm<float, GIT, false, false, IND><<<dim3(MROWS/64, G3/128), 256, 0, stream>>>(
      state, w_ih, b_ih, gi, G3);

  // pick scan variant by achievable occupancy (pure host query, capture-safe)
  {
    const int* dones_a = dones; const float* whh_a = w_hh; const float* bhh_a = b_hh;
    const float* bih_a = b_ih;
    void* args[] = { (void*)&gi, (void*)&dones_a, (void*)&whh_a, (void*)&bhh_a, (void*)&bih_a,
                     (void*)&c_arr, (void*)&h_buf, (void*)&counters, (void*)&gru_out, (void*)&hx_out };
    auto k2 = rnnq_scan<GIT, 2>;
    int nb2 = 0;
    (void)hipOccupancyMaxActiveBlocksPerMultiprocessor(&nb2, reinterpret_cast<const void*>(k2), 256, 0);
    if (nb2 >= 2) {
      (void)hipLaunchCooperativeKernel(reinterpret_cast<const void*>(k2),
                                       dim3(JGROUPS * 64), dim3(256), args, 0, stream);
    } else {
      auto k4 = rnnq_scan<GIT, 4>;
      (void)hipLaunchCooperativeKernel(reinterpret_cast<const void*>(k4),
                                       dim3(JGROUPS * 32), dim3(256), args, 0, stream);
    }
  }

  rnnq_gemm<float, YT, true, true, HID><<<dim3(MROWS/64, HID/128), 256, 0, stream>>>(
      gru_out, fc0_w, fc0_b, y0, HID);
  rnnq_gemm<YT, YT, false, true, HID><<<dim3(MROWS/64, HID/128), 256, 0, stream>>>(
      y0, fc1_w, fc1_b, y1, HID);
  rnnq_fc2<YT><<<MROWS/32, 256, 0, stream>>>(y1, fc2_w, fc2_b, q_out);
}

extern "C" void kernel_launch(void* const* d_in, const int* in_sizes, int n_in,
                              void* d_out, int out_size, void* d_ws, size_t ws_size,
                              hipStream_t stream) {
  const float* state = (const float*)d_in[0];
  const float* h0    = (const float*)d_in[1];
  const int*   dones = (const int*)d_in[2];
  const float* w_ih  = (const float*)d_in[3];
  const float* w_hh  = (const float*)d_in[4];
  const float* b_ih  = (const float*)d_in[5];
  const float* b_hh  = (const float*)d_in[6];
  const float* fc0_w = (const float*)d_in[7];
  const float* fc0_b = (const float*)d_in[8];
  const float* fc1_w = (const float*)d_in[9];
  const float* fc1_b = (const float*)d_in[10];
  const float* fc2_w = (const float*)d_in[11];
  const float* fc2_b = (const float*)d_in[12];

  float* q_out   = (float*)d_out;                       // [64,2048,18]
  float* gru_out = q_out + (size_t)MROWS * ACTD;        // [64,2048,256]
  float* hx_out  = gru_out + (size_t)MROWS * HID;       // [1,64,256]
  char* ws = (char*)d_ws;

  const size_t GI_F32  = (size_t)MROWS * G3 * 4;        // 402,653,184
  const size_t GI_BF16 = (size_t)MROWS * G3 * 2;        // 201,326,592
  const size_t Y_F32   = (size_t)MROWS * HID * 4;       // 134,217,728
  const size_t Y_BF16  = (size_t)MROWS * HID * 2;       //  67,108,864
  const size_t TAIL    = 262144 + 256 + 4096;

  if (ws_size >= GI_F32 + TAIL) {
    // mode 0: gi fp32, activations fp32 (y0/y1 alias the dead gi region)
    run_pipeline<float, float>(state, h0, dones, w_ih, w_hh, b_ih, b_hh,
                               fc0_w, fc0_b, fc1_w, fc1_b, fc2_w, fc2_b,
                               q_out, gru_out, hx_out,
                               ws, Y_F32, GI_F32, stream);
  } else if (ws_size >= 2 * Y_F32 + TAIL) {
    // mode 1: gi bf16, y fp32; tail lives after the y region (gi dead by then is fine,
    // h_buf/c/counters are only alive during scan, placed past max(gi,y) extent)
    run_pipeline<unsigned short, float>(state, h0, dones, w_ih, w_hh, b_ih, b_hh,
                                        fc0_w, fc0_b, fc1_w, fc1_b, fc2_w, fc2_b,
                                        q_out, gru_out, hx_out,
                                        ws, Y_F32, 2 * Y_F32, stream);
  } else {
    // mode 2: everything bf16 in workspace
    run_pipeline<unsigned short, unsigned short>(state, h0, dones, w_ih, w_hh, b_ih, b_hh,
                                                 fc0_w, fc0_b, fc1_w, fc1_b, fc2_w, fc2_b,
                                                 q_out, gru_out, hx_out,
                                                 ws, Y_BF16, GI_BF16, stream);
  }
}

// Round 2
// 5543.404 us; speedup vs baseline: 9.0719x; 9.0719x over previous
//
#include <hip/hip_runtime.h>
#include <stdint.h>

#define NB    64
#define LSEQ  2048
#define IND   128
#define HID   256
#define ACTD  18
#define G3    768            // 3*HID
#define MROWS (NB*LSEQ)      // 131072

typedef _Float16 half_t;
typedef half_t half2_t __attribute__((ext_vector_type(2)));

// ---------------- dtype helpers (manual bf16) ------------
__device__ __forceinline__ float bf2f(unsigned short u) { return __uint_as_float(((unsigned)u) << 16); }
__device__ __forceinline__ unsigned short f2bf(float f) {
  unsigned u = __float_as_uint(f);
  return (unsigned short)((u + 0x7FFFu + ((u >> 16) & 1u)) >> 16);
}
template<typename T> __device__ __forceinline__ float ldv(const T* p);
template<> __device__ __forceinline__ float ldv<float>(const float* p) { return *p; }
template<> __device__ __forceinline__ float ldv<unsigned short>(const unsigned short* p) { return bf2f(*p); }
template<typename T> __device__ __forceinline__ void stv(T* p, float v);
template<> __device__ __forceinline__ void stv<float>(float* p, float v) { *p = v; }
template<> __device__ __forceinline__ void stv<unsigned short>(unsigned short* p, float v) { *p = f2bf(v); }
template<typename T> __device__ __forceinline__ float4 ld4(const T* p);
template<> __device__ __forceinline__ float4 ld4<float>(const float* p) { return *(const float4*)p; }
template<> __device__ __forceinline__ float4 ld4<unsigned short>(const unsigned short* p) {
  ushort4 u = *(const ushort4*)p;
  float4 r; r.x = bf2f(u.x); r.y = bf2f(u.y); r.z = bf2f(u.z); r.w = bf2f(u.w); return r;
}

__device__ __forceinline__ float fdot2f(half2_t a, half2_t b, float c) {
#if __has_builtin(__builtin_amdgcn_fdot2)
  return __builtin_amdgcn_fdot2(a, b, c, false);
#else
  return fmaf((float)a.x, (float)b.x, fmaf((float)a.y, (float)b.y, c));
#endif
}

__device__ __forceinline__ float sigmoid_f(float x) { return 1.f / (1.f + __expf(-x)); }
__device__ __forceinline__ float tanh_f(float x) {
  const float t = __expf(-2.f * fabsf(x));
  const float r = (1.f - t) / (1.f + t);
  return x < 0.f ? -r : r;
}

// ---------------- generic fp32-accumulate GEMM: C[M,N] = op(A[M,K]) * W[N,K]^T + b --
// tile 64 x 128, K-chunks of 32, micro 4x8 per thread, 256 threads
template<typename IT, typename OT, bool RELU_IN, bool RELU_OUT, int K>
__global__ __launch_bounds__(256) void rnnq_gemm(const IT* __restrict__ A, const float* __restrict__ W,
                                                 const float* __restrict__ bias, OT* __restrict__ C,
                                                 int N) {
  __shared__ float At[32][68];
  __shared__ float Wt[32][136];
  const int t  = threadIdx.x;
  const long m0 = (long)blockIdx.x * 64;
  const int n0 = blockIdx.y * 128;
  const int ty = t >> 4, tx = t & 15;
  const int sr = t >> 2, skq = (t & 3) * 4;
  const int wc = t >> 1, wkh = (t & 1) * 16;
  float acc[4][8] = {{0.f}};
  for (int kc = 0; kc < K; kc += 32) {
    float4 a0 = ld4(A + (m0 + sr) * (size_t)K + kc + skq);
    float4 a1 = ld4(A + (m0 + sr) * (size_t)K + kc + skq + 16);
    if (RELU_IN) {
      a0.x = fmaxf(a0.x, 0.f); a0.y = fmaxf(a0.y, 0.f); a0.z = fmaxf(a0.z, 0.f); a0.w = fmaxf(a0.w, 0.f);
      a1.x = fmaxf(a1.x, 0.f); a1.y = fmaxf(a1.y, 0.f); a1.z = fmaxf(a1.z, 0.f); a1.w = fmaxf(a1.w, 0.f);
    }
    const float* wp = W + (size_t)(n0 + wc) * K + kc + wkh;
    float4 w0 = *(const float4*)(wp + 0);
    float4 w1 = *(const float4*)(wp + 4);
    float4 w2 = *(const float4*)(wp + 8);
    float4 w3 = *(const float4*)(wp + 12);
    At[skq+0][sr] = a0.x; At[skq+1][sr] = a0.y; At[skq+2][sr] = a0.z; At[skq+3][sr] = a0.w;
    At[skq+16][sr] = a1.x; At[skq+17][sr] = a1.y; At[skq+18][sr] = a1.z; At[skq+19][sr] = a1.w;
    Wt[wkh+0][wc] = w0.x; Wt[wkh+1][wc] = w0.y; Wt[wkh+2][wc] = w0.z; Wt[wkh+3][wc] = w0.w;
    Wt[wkh+4][wc] = w1.x; Wt[wkh+5][wc] = w1.y; Wt[wkh+6][wc] = w1.z; Wt[wkh+7][wc] = w1.w;
    Wt[wkh+8][wc] = w2.x; Wt[wkh+9][wc] = w2.y; Wt[wkh+10][wc] = w2.z; Wt[wkh+11][wc] = w2.w;
    Wt[wkh+12][wc] = w3.x; Wt[wkh+13][wc] = w3.y; Wt[wkh+14][wc] = w3.z; Wt[wkh+15][wc] = w3.w;
    __syncthreads();
    #pragma unroll
    for (int k = 0; k < 32; ++k) {
      const float4 av  = *(const float4*)&At[k][ty*4];
      const float4 bv0 = *(const float4*)&Wt[k][tx*8];
      const float4 bv1 = *(const float4*)&Wt[k][tx*8+4];
      const float am[4] = {av.x, av.y, av.z, av.w};
      const float bm[8] = {bv0.x, bv0.y, bv0.z, bv0.w, bv1.x, bv1.y, bv1.z, bv1.w};
      #pragma unroll
      for (int i = 0; i < 4; ++i)
        #pragma unroll
        for (int jj = 0; jj < 8; ++jj)
          acc[i][jj] = fmaf(am[i], bm[jj], acc[i][jj]);
    }
    __syncthreads();
  }
  #pragma unroll
  for (int i = 0; i < 4; ++i) {
    const long r = m0 + ty*4 + i;
    OT* cp = C + r * (size_t)N + n0 + tx*8;
    #pragma unroll
    for (int jj = 0; jj < 8; ++jj) {
      float v = acc[i][jj] + bias[n0 + tx*8 + jj];
      if (RELU_OUT) v = fmaxf(v, 0.f);
      stv(cp + jj, v);
    }
  }
}

// ---------------- fc2: Q[131072,18] = X[131072,256] * W2[18,256]^T + b2 -------------
template<typename YT>
__global__ __launch_bounds__(256) void rnnq_fc2(const YT* __restrict__ X, const float* __restrict__ W2,
                                                const float* __restrict__ b2, float* __restrict__ Q) {
  __shared__ float xs[32][260];
  __shared__ float ws2[ACTD][260];
  const int t = threadIdx.x;
  const long r0 = (long)blockIdx.x * 32;
  for (int i = t; i < 32*64; i += 256) {
    const int r = i >> 6, c4 = (i & 63) * 4;
    const float4 v = ld4(X + (r0 + r) * (size_t)HID + c4);
    *(float4*)&xs[r][c4] = v;
  }
  for (int i = t; i < ACTD*64; i += 256) {
    const int a = i >> 6, c4 = (i & 63) * 4;
    *(float4*)&ws2[a][c4] = *(const float4*)(W2 + a*HID + c4);
  }
  __syncthreads();
  for (int idx = t; idx < 32*ACTD; idx += 256) {
    const int r = idx / ACTD, a = idx - r*ACTD;
    float s0 = 0.f, s1 = 0.f;
    #pragma unroll
    for (int k4 = 0; k4 < HID/4; k4 += 2) {
      const float4 xv = *(const float4*)&xs[r][k4*4];
      const float4 wv = *(const float4*)&ws2[a][k4*4];
      s0 = fmaf(xv.x, wv.x, s0); s0 = fmaf(xv.y, wv.y, s0);
      s0 = fmaf(xv.z, wv.z, s0); s0 = fmaf(xv.w, wv.w, s0);
      const float4 xv2 = *(const float4*)&xs[r][k4*4+4];
      const float4 wv2 = *(const float4*)&ws2[a][k4*4+4];
      s1 = fmaf(xv2.x, wv2.x, s1); s1 = fmaf(xv2.y, wv2.y, s1);
      s1 = fmaf(xv2.z, wv2.z, s1); s1 = fmaf(xv2.w, wv2.w, s1);
    }
    Q[(r0 + r) * ACTD + a] = s0 + s1 + b2[a];
  }
}

// ---------------- the scan: one block per row (64 main + 64 virtual), zero inter-block sync
// 512 threads: thread = (jg = t>>3 owns j0=jg*4..+3, kq = t&7 owns k=kq*32..+31).
// w_hh held as packed f16 in registers (192 VGPRs/thread); h f16 in LDS (double buffer);
// fp32 h / accumulate everywhere else. One __syncthreads per step.
template<typename GIT>
__global__ __launch_bounds__(512, 2) void rnnq_scan1(
    const GIT* __restrict__ gi, const int* __restrict__ dones,
    const float* __restrict__ w_hh, const float* __restrict__ b_hh, const float* __restrict__ b_ih,
    const float* __restrict__ h0, float* __restrict__ gru_out, float* __restrict__ next_hx) {
  const int row = blockIdx.x;       // 0..127
  const int n = row & 63;
  const bool is_main = row < 64;
  const int t = threadIdx.x;
  const int jg = t >> 3;            // 0..63
  const int kq = t & 7;             // 0..7
  const int j0 = jg * 4;
  const bool epi = (kq == 0);

  __shared__ half2_t hb[2][136];    // h pairs: hb[buf][k2] = (h[2k2], h[2k2+1])
  __shared__ float sbih[G3];
  __shared__ float sbhh[G3];
  __shared__ int cred[8];

  // ---- c = last done index for this n ----
  int cmax = 0;
  for (int i = t; i < LSEQ; i += 512) if (dones[n*LSEQ + i]) cmax = i;  // ascending i -> keeps max
  #pragma unroll
  for (int m = 1; m < 64; m <<= 1) { int o = __shfl_xor(cmax, m, 64); cmax = cmax > o ? cmax : o; }
  if ((t & 63) == 0) cred[t >> 6] = cmax;
  for (int i = t; i < G3; i += 512) { sbih[i] = b_ih[i]; sbhh[i] = b_hh[i]; }
  __syncthreads();
  int c = cred[0];
  #pragma unroll
  for (int w = 1; w < 8; ++w) c = c > cred[w] ? c : cred[w];
  const int off = is_main ? 0 : c;

  // ---- load & pack this thread's w_hh slice: [3 gates][4 j][32 k] as 16 half2 each ----
  half2_t wpk[3][4][16];
  #pragma unroll
  for (int g = 0; g < 3; ++g)
    #pragma unroll
    for (int jj = 0; jj < 4; ++jj) {
      const float* wp = w_hh + ((size_t)(g*HID + j0 + jj))*HID + kq*32;
      #pragma unroll
      for (int q2 = 0; q2 < 8; ++q2) {
        const float4 v = *(const float4*)(wp + q2*4);
        half2_t a; a.x = (half_t)v.x; a.y = (half_t)v.y;
        half2_t b; b.x = (half_t)v.z; b.y = (half_t)v.w;
        wpk[g][jj][q2*2]   = a;
        wpk[g][jj][q2*2+1] = b;
      }
    }

  // ---- initial h, gi, done flag (epi lanes only) ----
  float hprev[4] = {0.f, 0.f, 0.f, 0.f};
  float4 gr4, gz4, gn4;
  int dcur = 0;
  if (epi) {
    const float4 hp = *(const float4*)(h0 + n*HID + j0);
    hprev[0] = hp.x; hprev[1] = hp.y; hprev[2] = hp.z; hprev[3] = hp.w;
    half2_t p0; p0.x = (half_t)hp.x; p0.y = (half_t)hp.y;
    half2_t p1; p1.x = (half_t)hp.z; p1.y = (half_t)hp.w;
    hb[0][jg*2]   = p0;
    hb[0][jg*2+1] = p1;
    const int idx0 = off;
    dcur = dones[n*LSEQ + idx0];
    const GIT* gp = gi + ((size_t)n*LSEQ + idx0) * G3;
    gr4 = ld4(gp + j0); gz4 = ld4(gp + HID + j0); gn4 = ld4(gp + 2*HID + j0);
  }
  __syncthreads();

  for (int step = 0; step < LSEQ; ++step) {
    const int cur = step & 1, nxt = cur ^ 1;
    // ---- matvec partials: 12 accumulators, 192 dot2 ----
    float acc[3][4];
    #pragma unroll
    for (int g = 0; g < 3; ++g)
      #pragma unroll
      for (int jj = 0; jj < 4; ++jj) acc[g][jj] = 0.f;
    #pragma unroll
    for (int q4 = 0; q4 < 4; ++q4) {
      half2_t hv[4];
      *(float4*)hv = *(const float4*)&hb[cur][kq*16 + q4*4];
      #pragma unroll
      for (int g = 0; g < 3; ++g)
        #pragma unroll
        for (int jj = 0; jj < 4; ++jj) {
          acc[g][jj] = fdot2f(wpk[g][jj][q4*4+0], hv[0], acc[g][jj]);
          acc[g][jj] = fdot2f(wpk[g][jj][q4*4+1], hv[1], acc[g][jj]);
          acc[g][jj] = fdot2f(wpk[g][jj][q4*4+2], hv[2], acc[g][jj]);
          acc[g][jj] = fdot2f(wpk[g][jj][q4*4+3], hv[3], acc[g][jj]);
        }
    }
    // ---- butterfly reduce over kq (lane bits 0..2) ----
    #pragma unroll
    for (int g = 0; g < 3; ++g)
      #pragma unroll
      for (int jj = 0; jj < 4; ++jj) {
        float s = acc[g][jj];
        s += __shfl_xor(s, 1, 64);
        s += __shfl_xor(s, 2, 64);
        s += __shfl_xor(s, 4, 64);
        acc[g][jj] = s;
      }
    if (epi) {
      const float m = dcur ? 0.f : 1.f;
      const float4 bhr4 = *(const float4*)&sbhh[j0];
      const float4 bhz4 = *(const float4*)&sbhh[HID + j0];
      const float4 bhn4 = *(const float4*)&sbhh[2*HID + j0];
      const float* bhr = (const float*)&bhr4;
      const float* bhz = (const float*)&bhz4;
      const float* bhn = (const float*)&bhn4;
      const float* gr = (const float*)&gr4;
      const float* gz = (const float*)&gz4;
      const float* gn = (const float*)&gn4;
      float hnew[4];
      #pragma unroll
      for (int jj = 0; jj < 4; ++jj) {
        const float hold = m * hprev[jj];
        const float rr = sigmoid_f(gr[jj] + m * acc[0][jj] + bhr[jj]);
        const float zz = sigmoid_f(gz[jj] + m * acc[1][jj] + bhz[jj]);
        const float nn = tanh_f(gn[jj] + rr * (m * acc[2][jj] + bhn[jj]));
        hnew[jj] = (1.f - zz) * nn + zz * hold;
        hprev[jj] = hnew[jj];
      }
      // publish h for next step (f16 pairs, other buffer)
      half2_t p0; p0.x = (half_t)hnew[0]; p0.y = (half_t)hnew[1];
      half2_t p1; p1.x = (half_t)hnew[2]; p1.y = (half_t)hnew[3];
      hb[nxt][jg*2]   = p0;
      hb[nxt][jg*2+1] = p1;
      if (is_main) {
        float4 o; o.x = hnew[0]; o.y = hnew[1]; o.z = hnew[2]; o.w = hnew[3];
        *(float4*)(gru_out + ((size_t)n*LSEQ + step)*HID + j0) = o;
      } else if (step == LSEQ - 1) {
        float4 o; o.x = hnew[0]; o.y = hnew[1]; o.z = hnew[2]; o.w = hnew[3];
        *(float4*)(next_hx + n*HID + j0) = o;
      }
      // prefetch next step's gi + done
      if (step + 1 < LSEQ) {
        const int idx = off + step + 1;
        if (idx < LSEQ) {
          dcur = dones[n*LSEQ + idx];
          const GIT* gp = gi + ((size_t)n*LSEQ + idx) * G3;
          gr4 = ld4(gp + j0); gz4 = ld4(gp + HID + j0); gn4 = ld4(gp + 2*HID + j0);
        } else {
          dcur = 0;
          gr4 = *(const float4*)&sbih[j0];
          gz4 = *(const float4*)&sbih[HID + j0];
          gn4 = *(const float4*)&sbih[2*HID + j0];
        }
      }
    }
    __syncthreads();
  }
}

// ---------------- host-side pipeline ----------------
template<typename GIT, typename YT>
static void run_pipeline(const float* state, const float* h0, const int* dones,
                         const float* w_ih, const float* w_hh, const float* b_ih, const float* b_hh,
                         const float* fc0_w, const float* fc0_b, const float* fc1_w, const float* fc1_b,
                         const float* fc2_w, const float* fc2_b,
                         float* q_out, float* gru_out, float* hx_out,
                         char* ws, size_t y1_off, hipStream_t stream) {
  GIT* gi = (GIT*)ws;
  YT* y0 = (YT*)ws;                       // aliases gi (gi dead after scan)
  YT* y1 = (YT*)(ws + y1_off);

  rnnq_gemm<float, GIT, false, false, IND><<<dim3(MROWS/64, G3/128), 256, 0, stream>>>(
      state, w_ih, b_ih, gi, G3);
  rnnq_scan1<GIT><<<128, 512, 0, stream>>>(gi, dones, w_hh, b_hh, b_ih, h0, gru_out, hx_out);
  rnnq_gemm<float, YT, true, true, HID><<<dim3(MROWS/64, HID/128), 256, 0, stream>>>(
      gru_out, fc0_w, fc0_b, y0, HID);
  rnnq_gemm<YT, YT, false, true, HID><<<dim3(MROWS/64, HID/128), 256, 0, stream>>>(
      y0, fc1_w, fc1_b, y1, HID);
  rnnq_fc2<YT><<<MROWS/32, 256, 0, stream>>>(y1, fc2_w, fc2_b, q_out);
}

extern "C" void kernel_launch(void* const* d_in, const int* in_sizes, int n_in,
                              void* d_out, int out_size, void* d_ws, size_t ws_size,
                              hipStream_t stream) {
  const float* state = (const float*)d_in[0];
  const float* h0    = (const float*)d_in[1];
  const int*   dones = (const int*)d_in[2];
  const float* w_ih  = (const float*)d_in[3];
  const float* w_hh  = (const float*)d_in[4];
  const float* b_ih  = (const float*)d_in[5];
  const float* b_hh  = (const float*)d_in[6];
  const float* fc0_w = (const float*)d_in[7];
  const float* fc0_b = (const float*)d_in[8];
  const float* fc1_w = (const float*)d_in[9];
  const float* fc1_b = (const float*)d_in[10];
  const float* fc2_w = (const float*)d_in[11];
  const float* fc2_b = (const float*)d_in[12];

  float* q_out   = (float*)d_out;                       // [64,2048,18]
  float* gru_out = q_out + (size_t)MROWS * ACTD;        // [64,2048,256]
  float* hx_out  = gru_out + (size_t)MROWS * HID;       // [1,64,256]
  char* ws = (char*)d_ws;

  const size_t GI_F32  = (size_t)MROWS * G3 * 4;        // 402,653,184
  const size_t Y_F32   = (size_t)MROWS * HID * 4;       // 134,217,728
  const size_t Y_BF16  = (size_t)MROWS * HID * 2;       //  67,108,864

  if (ws_size >= GI_F32) {
    run_pipeline<float, float>(state, h0, dones, w_ih, w_hh, b_ih, b_hh,
                               fc0_w, fc0_b, fc1_w, fc1_b, fc2_w, fc2_b,
                               q_out, gru_out, hx_out, ws, Y_F32, stream);
  } else if (ws_size >= 2 * Y_F32) {
    run_pipeline<unsigned short, float>(state, h0, dones, w_ih, w_hh, b_ih, b_hh,
                                        fc0_w, fc0_b, fc1_w, fc1_b, fc2_w, fc2_b,
                                        q_out, gru_out, hx_out, ws, Y_F32, stream);
  } else {
    run_pipeline<unsigned short, unsigned short>(state, h0, dones, w_ih, w_hh, b_ih, b_hh,
                                                 fc0_w, fc0_b, fc1_w, fc1_b, fc2_w, fc2_b,
                                                 q_out, gru_out, hx_out, ws, Y_BF16, stream);
  }
}